// Round 5
// baseline (383.055 us; speedup 1.0000x reference)
//
#include <hip/hip_runtime.h>
#include <math.h>

constexpr int N_NODES = 50000;
constexpr int N_PAD   = 50048;    // 391 * 128, padded rows for tile overrun
constexpr int N_EDGES = 400000;
constexpr int IN_F = 512;
constexpr int HEADS = 8;
constexpr int OUT_F = 64;
constexpr int HF = 512;           // HEADS * OUT_F
constexpr float NEG = 0.2f;

typedef __bf16 bf16x8 __attribute__((ext_vector_type(8)));
typedef float  f32x4  __attribute__((ext_vector_type(4)));

__device__ __forceinline__ unsigned short f2bf(float f) {
    unsigned u = __float_as_uint(f);
    u += 0x7fffu + ((u >> 16) & 1u);   // round-to-nearest-even (inputs finite)
    return (unsigned short)(u >> 16);
}
__device__ __forceinline__ unsigned packbf2(float lo, float hi) {
    return (unsigned)f2bf(lo) | ((unsigned)f2bf(hi) << 16);
}

// ---------------------------------------------------------------------------
// K14: merged dispatch — [0,256): W_val transpose->bf16; [256,289): fold
// attention vectors; [289,...): dst-degree histogram. (deg zeroed by memset.)
// ---------------------------------------------------------------------------
constexpr int K14_HIST0 = 289;
constexpr int K14_BLOCKS = K14_HIST0 + (N_EDGES + 255) / 256;   // 289 + 1563

__global__ __launch_bounds__(256) void k14_misc(
        const float* __restrict__ W_val, unsigned short* __restrict__ Wt,
        const float* __restrict__ W_src, const float* __restrict__ b_src,
        const float* __restrict__ W_dst, const float* __restrict__ b_dst,
        const float* __restrict__ attn_l, const float* __restrict__ attn_r,
        float* __restrict__ w_l, float* __restrict__ w_r,
        float* __restrict__ c_l, float* __restrict__ c_r,
        const int* __restrict__ dst, int* __restrict__ deg) {
    __shared__ float tile[32][33];
    int b = blockIdx.x, t = threadIdx.x;
    if (b < 256) {
        int bi = b >> 4, bj = b & 15;
        for (int i = t; i < 1024; i += 256) {
            int r = i >> 5, c = i & 31;
            tile[r][c] = W_val[(size_t)(bi * 32 + r) * HF + bj * 32 + c];
        }
        __syncthreads();
        for (int i = t; i < 1024; i += 256) {
            int r = i >> 5, c = i & 31;
            Wt[(size_t)(bj * 32 + r) * IN_F + bi * 32 + c] = f2bf(tile[c][r]);
        }
    } else if (b < K14_HIST0) {
        int gid = (b - 256) * 256 + t;
        if (gid < 4096) {
            int k = gid >> 3, h = gid & 7;
            float s = 0.f;
            #pragma unroll 8
            for (int f = 0; f < OUT_F; ++f) s += W_src[k * HF + h * OUT_F + f] * attn_l[h * OUT_F + f];
            w_l[k * 8 + h] = s;
        } else if (gid < 8192) {
            int g = gid - 4096;
            int k = g >> 3, h = g & 7;
            float s = 0.f;
            #pragma unroll 8
            for (int f = 0; f < OUT_F; ++f) s += W_dst[k * HF + h * OUT_F + f] * attn_r[h * OUT_F + f];
            w_r[k * 8 + h] = s;
        } else if (gid < 8192 + 16) {
            int g = gid - 8192;
            int h = g & 7;
            float s = 0.f;
            if (g < 8) {
                for (int f = 0; f < OUT_F; ++f) s += b_src[h * OUT_F + f] * attn_l[h * OUT_F + f];
                c_l[h] = s;
            } else {
                for (int f = 0; f < OUT_F; ++f) s += b_dst[h * OUT_F + f] * attn_r[h * OUT_F + f];
                c_r[h] = s;
            }
        }
    } else {
        int e = (b - K14_HIST0) * 256 + t;
        if (e < N_EDGES) atomicAdd(&deg[dst[e]], 1);
    }
}

// ---------------------------------------------------------------------------
// K0F: fused feat fp32->bf16 conversion + el/er (fp32 precision).
// ---------------------------------------------------------------------------
constexpr int K0F_GRID = 1024;

__global__ __launch_bounds__(256, 2) void k0_fused(
        const float* __restrict__ feat,
        const float* __restrict__ w_l, const float* __restrict__ w_r,
        const float* __restrict__ c_l, const float* __restrict__ c_r,
        unsigned short* __restrict__ feat_bf,
        float* __restrict__ el, float* __restrict__ er) {
    __shared__ float4 lw[2048];            // w_l (0..1023) || w_r (1024..2047)
    int t = threadIdx.x;
    int lane = t & 63, wv = t >> 6;

    const float4* gl = (const float4*)w_l;
    const float4* gr = (const float4*)w_r;
    #pragma unroll
    for (int p = 0; p < 8; ++p) {
        int i = t + 256 * p;
        int sw = i ^ ((i >> 4) & 7);
        lw[sw] = (i < 1024) ? gl[i] : gr[i - 1024];
    }
    __syncthreads();

    float4 wl0[8], wl1[8], wr0[8], wr1[8];
    #pragma unroll
    for (int j = 0; j < 8; ++j) {
        int i0 = 16 * lane + 2 * j;
        wl0[j] = lw[i0 ^ ((i0 >> 4) & 7)];
        int i1 = i0 + 1;
        wl1[j] = lw[i1 ^ ((i1 >> 4) & 7)];
        int i2 = 1024 + i0;
        wr0[j] = lw[i2 ^ ((i2 >> 4) & 7)];
        int i3 = i2 + 1;
        wr1[j] = lw[i3 ^ ((i3 >> 4) & 7)];
    }

    int idx = ((lane & 1) << 3) | ((lane & 2) << 1) | ((lane & 4) >> 1) | ((lane & 8) >> 3);
    int oh = idx & 7, oside = idx >> 3;
    float cadd = 0.f;
    if (lane < 16) cadd = oside ? c_r[oh] : c_l[oh];

    const int NQ = N_NODES / 4;            // 12500, exact
    int q = blockIdx.x;
    if (q >= NQ) return;

    float4 f0, f1;
    {
        const float* fr = feat + (size_t)(q * 4 + wv) * IN_F + lane * 8;
        f0 = *(const float4*)fr;
        f1 = *(const float4*)(fr + 4);
    }

    while (true) {
        int qn = q + K0F_GRID;
        float4 n0, n1;
        if (qn < NQ) {
            const float* fr = feat + (size_t)(qn * 4 + wv) * IN_F + lane * 8;
            n0 = *(const float4*)fr;
            n1 = *(const float4*)(fr + 4);
        }

        int row = q * 4 + wv;
        uint4 vv;
        vv.x = packbf2(f0.x, f0.y); vv.y = packbf2(f0.z, f0.w);
        vv.z = packbf2(f1.x, f1.y); vv.w = packbf2(f1.z, f1.w);
        *(uint4*)(feat_bf + (size_t)row * IN_F + lane * 8) = vv;

        float v[16];
        #pragma unroll
        for (int c = 0; c < 16; ++c) v[c] = 0.f;
        float ff[8] = {f0.x, f0.y, f0.z, f0.w, f1.x, f1.y, f1.z, f1.w};
        #pragma unroll
        for (int j = 0; j < 8; ++j) {
            float f = ff[j];
            v[0]  = fmaf(f, wl0[j].x, v[0]);
            v[1]  = fmaf(f, wl0[j].y, v[1]);
            v[2]  = fmaf(f, wl0[j].z, v[2]);
            v[3]  = fmaf(f, wl0[j].w, v[3]);
            v[4]  = fmaf(f, wl1[j].x, v[4]);
            v[5]  = fmaf(f, wl1[j].y, v[5]);
            v[6]  = fmaf(f, wl1[j].z, v[6]);
            v[7]  = fmaf(f, wl1[j].w, v[7]);
            v[8]  = fmaf(f, wr0[j].x, v[8]);
            v[9]  = fmaf(f, wr0[j].y, v[9]);
            v[10] = fmaf(f, wr0[j].z, v[10]);
            v[11] = fmaf(f, wr0[j].w, v[11]);
            v[12] = fmaf(f, wr1[j].x, v[12]);
            v[13] = fmaf(f, wr1[j].y, v[13]);
            v[14] = fmaf(f, wr1[j].z, v[14]);
            v[15] = fmaf(f, wr1[j].w, v[15]);
        }

        #pragma unroll
        for (int j = 0; j < 8; ++j) {       // mask 1: idx bit3 <- lane bit0
            float a = v[j], b = v[j + 8];
            float send = (lane & 1) ? a : b;
            float recv = __shfl_xor(send, 1, 64);
            v[j] = ((lane & 1) ? b : a) + recv;
        }
        #pragma unroll
        for (int j = 0; j < 4; ++j) {       // mask 2: idx bit2 <- lane bit1
            float a = v[j], b = v[j + 4];
            float send = (lane & 2) ? a : b;
            float recv = __shfl_xor(send, 2, 64);
            v[j] = ((lane & 2) ? b : a) + recv;
        }
        #pragma unroll
        for (int j = 0; j < 2; ++j) {       // mask 4: idx bit1 <- lane bit2
            float a = v[j], b = v[j + 2];
            float send = (lane & 4) ? a : b;
            float recv = __shfl_xor(send, 4, 64);
            v[j] = ((lane & 4) ? b : a) + recv;
        }
        {                                   // mask 8: idx bit0 <- lane bit3
            float a = v[0], b = v[1];
            float send = (lane & 8) ? a : b;
            float recv = __shfl_xor(send, 8, 64);
            v[0] = ((lane & 8) ? b : a) + recv;
        }
        float tot = v[0];
        tot += __shfl_xor(tot, 16, 64);
        tot += __shfl_xor(tot, 32, 64);

        if (lane < 16) {
            float o = tot + cadd;
            if (oside) er[(size_t)row * 8 + oh] = o;
            else       el[(size_t)row * 8 + oh] = o;
        }

        if (qn >= NQ) break;
        q = qn; f0 = n0; f1 = n1;
    }
}

// ---------------------------------------------------------------------------
// KS: single-dispatch exclusive scan (redundant-prefix per block, no serial).
// ---------------------------------------------------------------------------
__global__ __launch_bounds__(1024) void kS_scan(const int* __restrict__ deg,
                                                int* __restrict__ offs,
                                                int* __restrict__ cursor) {
    __shared__ int wsum[16];
    __shared__ int base_s;
    int b = blockIdx.x, t = threadIdx.x;
    int lane = t & 63, wid = t >> 6;

    int pre = 0;
    for (int i = t; i < b * 1024; i += 1024) pre += deg[i];
    #pragma unroll
    for (int off = 32; off; off >>= 1) pre += __shfl_down(pre, (unsigned)off, 64);
    if (lane == 0) wsum[wid] = pre;
    __syncthreads();
    if (t == 0) {
        int s = 0;
        for (int i = 0; i < 16; ++i) s += wsum[i];
        base_s = s;
    }
    __syncthreads();
    int base = base_s;
    __syncthreads();

    int i = b * 1024 + t;
    int v = (i < N_NODES) ? deg[i] : 0;
    int x = v;
    #pragma unroll
    for (int off = 1; off < 64; off <<= 1) {
        int y = __shfl_up(x, (unsigned)off, 64);
        if (lane >= off) x += y;
    }
    if (lane == 63) wsum[wid] = x;
    __syncthreads();
    if (wid == 0) {
        int s = (lane < 16) ? wsum[lane] : 0;
        #pragma unroll
        for (int off = 1; off < 16; off <<= 1) {
            int y = __shfl_up(s, (unsigned)off, 64);
            if (lane >= off) s += y;
        }
        if (lane < 16) wsum[lane] = s;
    }
    __syncthreads();
    int woff = wid ? wsum[wid - 1] : 0;
    if (i < N_NODES) {
        int excl = base + woff + x - v;
        offs[i] = excl;
        cursor[i] = excl;
    }
}

// ---------------------------------------------------------------------------
// K3: feat_v = feat @ W_val + b_val via bf16 MFMA (m97 structure, validated).
// R3's XCD-aware remap measured NEUTRAL (A-fetch not the bottleneck);
// reverted to the simple map.
// ---------------------------------------------------------------------------
__global__ __launch_bounds__(256) void k3_mfma(
        const unsigned short* __restrict__ Abf,
        const unsigned short* __restrict__ Bbf,
        const float* __restrict__ bias,
        unsigned short* __restrict__ C) {
    __shared__ unsigned short As[128 * 64];
    __shared__ unsigned short Bs[128 * 64];
    int tid = threadIdx.x;
    int w = tid >> 6, lane = tid & 63;
    int bm = blockIdx.x >> 2, bn = blockIdx.x & 3;
    int rowBase = bm * 128, colBase = bn * 128;
    int wm = w >> 1, wn = w & 1;
    int c15 = lane & 15, q = lane >> 4;

    f32x4 acc[4][4] = {};

    for (int k0 = 0; k0 < IN_F; k0 += 64) {
        #pragma unroll
        for (int rnd = 0; rnd < 4; ++rnd) {
            int e = w * 256 + rnd * 64 + lane;
            int r = e >> 3, p = e & 7;
            int lc = p ^ (r & 7);                  // XOR chunk swizzle
            const unsigned short* gA = Abf + (size_t)(rowBase + r) * IN_F + k0 + lc * 8;
            unsigned short* lA = &As[(w * 256 + rnd * 64) * 8];
            __builtin_amdgcn_global_load_lds(
                (const __attribute__((address_space(1))) unsigned int*)gA,
                (__attribute__((address_space(3))) unsigned int*)lA, 16, 0, 0);
            const unsigned short* gB = Bbf + (size_t)(colBase + r) * IN_F + k0 + lc * 8;
            unsigned short* lB = &Bs[(w * 256 + rnd * 64) * 8];
            __builtin_amdgcn_global_load_lds(
                (const __attribute__((address_space(1))) unsigned int*)gB,
                (__attribute__((address_space(3))) unsigned int*)lB, 16, 0, 0);
        }
        __syncthreads();

        #pragma unroll
        for (int ks = 0; ks < 2; ++ks) {
            bf16x8 a[4], b[4];
            #pragma unroll
            for (int mi = 0; mi < 4; ++mi) {
                int row = wm * 64 + mi * 16 + c15;
                int pc = (ks * 4 + q) ^ (row & 7);
                a[mi] = *(const bf16x8*)&As[row * 64 + pc * 8];
            }
            #pragma unroll
            for (int nj = 0; nj < 4; ++nj) {
                int row = wn * 64 + nj * 16 + c15;
                int pc = (ks * 4 + q) ^ (row & 7);
                b[nj] = *(const bf16x8*)&Bs[row * 64 + pc * 8];
            }
            #pragma unroll
            for (int mi = 0; mi < 4; ++mi)
                #pragma unroll
                for (int nj = 0; nj < 4; ++nj)
                    acc[mi][nj] = __builtin_amdgcn_mfma_f32_16x16x32_bf16(
                        a[mi], b[nj], acc[mi][nj], 0, 0, 0);
        }
        __syncthreads();
    }

    #pragma unroll
    for (int nj = 0; nj < 4; ++nj) {
        int col = colBase + wn * 64 + nj * 16 + c15;
        float bv = bias[col];
        #pragma unroll
        for (int mi = 0; mi < 4; ++mi) {
            int row0 = rowBase + wm * 64 + mi * 16 + q * 4;
            #pragma unroll
            for (int rg = 0; rg < 4; ++rg) {
                C[(size_t)(row0 + rg) * HF + col] = f2bf(acc[mi][nj][rg] + bv);
            }
        }
    }
}

// ---------------------------------------------------------------------------
// K6: counting-sort scatter ONLY (4B payload — minimal scattered write).
// ---------------------------------------------------------------------------
__global__ __launch_bounds__(256) void k6_scatter(
        const int* __restrict__ src, const int* __restrict__ dst,
        int* __restrict__ cursor, int* __restrict__ srcs) {
    int e = blockIdx.x * 256 + threadIdx.x;
    if (e < N_EDGES) {
        int pos = atomicAdd(&cursor[dst[e]], 1);
        srcs[pos] = src[e];
    }
}

// ---------------------------------------------------------------------------
// K8: fused edge-softmax + aggregation (R0 inner structure, proven 77-79 µs:
// one WAVE per node, lane owns a 16B uint4 chunk; 16B/lane gather is the
// instruction-efficiency sweet spot). NEW (R4): block-churn amortization —
// grid 3125, each block loops 4 chunk groups (16 nodes/block) so CUs aren't
// draining/refilling tiny avg-deg-8 workgroups (measured occupancy 34% at
// 12500 blocks). NO min-waves hint (R2 lesson: (256,8) forced VGPR 56->32
// and spilled acc[] -> 375 MB scratch writes). Atomic-free.
// ---------------------------------------------------------------------------
constexpr int K8_BLOCKS = 3125;            // 12500 chunks / 4 per block

__device__ __forceinline__ void accum8(float* acc, uint4 v, float w) {
    unsigned u;
    u = v.x;
    acc[0] = fmaf(w, __uint_as_float(u << 16), acc[0]);
    acc[1] = fmaf(w, __uint_as_float(u & 0xffff0000u), acc[1]);
    u = v.y;
    acc[2] = fmaf(w, __uint_as_float(u << 16), acc[2]);
    acc[3] = fmaf(w, __uint_as_float(u & 0xffff0000u), acc[3]);
    u = v.z;
    acc[4] = fmaf(w, __uint_as_float(u << 16), acc[4]);
    acc[5] = fmaf(w, __uint_as_float(u & 0xffff0000u), acc[5]);
    u = v.w;
    acc[6] = fmaf(w, __uint_as_float(u << 16), acc[6]);
    acc[7] = fmaf(w, __uint_as_float(u & 0xffff0000u), acc[7]);
}

__global__ __launch_bounds__(256) void k8_agg(
        const int* __restrict__ srcs, const int* __restrict__ offs,
        const int* __restrict__ deg,
        const float* __restrict__ el, const float* __restrict__ er,
        const uint4* __restrict__ feat_v,     // bf16 rows: 64 uint4 per row
        float* __restrict__ out) {
    int lane = threadIdx.x & 63;
    int wv = threadIdx.x >> 6;
    int h = lane >> 3;

    #pragma unroll 1
    for (int chunk = blockIdx.x; chunk < N_NODES / 4; chunk += K8_BLOCKS) {
        int n = chunk * 4 + wv;
        int start = offs[n], cnt = deg[n];
        float erh = er[(size_t)n * 8 + h];
        float acc[8] = {};
        float dsum = 0.f;

        for (int base = 0; base < cnt; base += 64) {
            int m = cnt - base; if (m > 64) m = 64;
            int s_all = (lane < m) ? srcs[start + base + lane] : 0;
            int i = 0;
            for (; i + 8 <= m; i += 8) {
                int s[8]; uint4 v[8]; float e[8];
                #pragma unroll
                for (int j = 0; j < 8; ++j) s[j] = __shfl(s_all, i + j, 64);
                #pragma unroll
                for (int j = 0; j < 8; ++j) v[j] = feat_v[(size_t)s[j] * 64 + lane];
                #pragma unroll
                for (int j = 0; j < 8; ++j) e[j] = el[(size_t)s[j] * 8 + h];
                #pragma unroll
                for (int j = 0; j < 8; ++j) {
                    float x = e[j] + erh;
                    x = (x >= 0.f) ? x : NEG * x;
                    float w = __expf(x);
                    dsum += w;
                    accum8(acc, v[j], w);
                }
            }
            for (; i < m; ++i) {
                int s0 = __shfl(s_all, i, 64);
                uint4 v0 = feat_v[(size_t)s0 * 64 + lane];
                float x = el[(size_t)s0 * 8 + h] + erh;
                x = (x >= 0.f) ? x : NEG * x;
                float w = __expf(x);
                dsum += w;
                accum8(acc, v0, w);
            }
        }

        float dn = 1.f / fmaxf(dsum, 1e-16f);
        float* op = out + (size_t)n * HF + lane * 8;
        *(float4*)op       = make_float4(acc[0] * dn, acc[1] * dn, acc[2] * dn, acc[3] * dn);
        *(float4*)(op + 4) = make_float4(acc[4] * dn, acc[5] * dn, acc[6] * dn, acc[7] * dn);
    }
}

// ---------------------------------------------------------------------------
extern "C" void kernel_launch(void* const* d_in, const int* in_sizes, int n_in,
                              void* d_out, int out_size, void* d_ws, size_t ws_size,
                              hipStream_t stream) {
    const float* feat   = (const float*)d_in[0];
    const int*   src    = (const int*)d_in[1];
    const int*   dst    = (const int*)d_in[2];
    const float* W_src  = (const float*)d_in[3];
    const float* b_src  = (const float*)d_in[4];
    const float* W_dst  = (const float*)d_in[5];
    const float* b_dst  = (const float*)d_in[6];
    const float* W_val  = (const float*)d_in[7];
    const float* b_val  = (const float*)d_in[8];
    const float* attn_l = (const float*)d_in[9];
    const float* attn_r = (const float*)d_in[10];
    float* out = (float*)d_out;

    char* ws = (char*)d_ws;
    size_t off = 0;
    auto alloc = [&](size_t bytes) -> void* {
        void* p = ws + off;
        off += (bytes + 255) & ~(size_t)255;
        return p;
    };

    unsigned short* feat_bf = (unsigned short*)alloc((size_t)N_PAD * IN_F * 2);
    unsigned short* Wt      = (unsigned short*)alloc((size_t)IN_F * HF * 2);
    unsigned short* feat_v  = (unsigned short*)alloc((size_t)N_PAD * HF * 2);
    float* w_l    = (float*)alloc(4096 * 4);
    float* w_r    = (float*)alloc(4096 * 4);
    float* c_l    = (float*)alloc(8 * 4);
    float* c_r    = (float*)alloc(8 * 4);
    float* el     = (float*)alloc((size_t)N_NODES * 8 * 4);
    float* er     = (float*)alloc((size_t)N_NODES * 8 * 4);
    int*   deg    = (int*)alloc((size_t)N_NODES * 4);
    int*   offs   = (int*)alloc((size_t)N_NODES * 4);
    int*   cursor = (int*)alloc((size_t)N_NODES * 4);
    int*   srcs   = (int*)alloc((size_t)N_EDGES * 4);
    (void)ws_size; (void)in_sizes; (void)n_in; (void)out_size;

    hipMemsetAsync(deg, 0, (size_t)N_NODES * 4, stream);
    k14_misc<<<K14_BLOCKS, 256, 0, stream>>>(W_val, Wt, W_src, b_src, W_dst, b_dst,
                                             attn_l, attn_r, w_l, w_r, c_l, c_r, dst, deg);
    k0_fused<<<K0F_GRID, 256, 0, stream>>>(feat, w_l, w_r, c_l, c_r, feat_bf, el, er);
    kS_scan<<<(N_NODES + 1023) / 1024, 1024, 0, stream>>>(deg, offs, cursor);
    k3_mfma<<<(N_PAD / 128) * 4, 256, 0, stream>>>(feat_bf, Wt, b_val, feat_v);
    k6_scatter<<<(N_EDGES + 255) / 256, 256, 0, stream>>>(src, dst, cursor, srcs);
    k8_agg<<<K8_BLOCKS, 256, 0, stream>>>(srcs, offs, deg, el, er,
                                          (const uint4*)feat_v, out);
}

// Round 6
// 369.110 us; speedup vs baseline: 1.0378x; 1.0378x over previous
//
#include <hip/hip_runtime.h>
#include <math.h>

constexpr int N_NODES = 50000;
constexpr int N_PAD   = 50048;    // 391 * 128, padded rows for tile overrun
constexpr int N_EDGES = 400000;
constexpr int IN_F = 512;
constexpr int HEADS = 8;
constexpr int OUT_F = 64;
constexpr int HF = 512;           // HEADS * OUT_F
constexpr float NEG = 0.2f;

typedef __bf16 bf16x8 __attribute__((ext_vector_type(8)));
typedef float  f32x4  __attribute__((ext_vector_type(4)));

__device__ __forceinline__ unsigned short f2bf(float f) {
    unsigned u = __float_as_uint(f);
    u += 0x7fffu + ((u >> 16) & 1u);   // round-to-nearest-even (inputs finite)
    return (unsigned short)(u >> 16);
}
__device__ __forceinline__ unsigned packbf2(float lo, float hi) {
    return (unsigned)f2bf(lo) | ((unsigned)f2bf(hi) << 16);
}

// ---------------------------------------------------------------------------
// K14: merged dispatch — [0,256): W_val transpose->bf16; [256,289): fold
// attention vectors into w_lr (bf16, [16 cols][512 k], col<8 = l-side heads,
// col>=8 = r-side) + c_lr[16] (bias dots); [289,...): dst-degree histogram.
// (deg zeroed by memset.)
// ---------------------------------------------------------------------------
constexpr int K14_HIST0 = 289;
constexpr int K14_BLOCKS = K14_HIST0 + (N_EDGES + 255) / 256;   // 289 + 1563

__global__ __launch_bounds__(256) void k14_misc(
        const float* __restrict__ W_val, unsigned short* __restrict__ Wt,
        const float* __restrict__ W_src, const float* __restrict__ b_src,
        const float* __restrict__ W_dst, const float* __restrict__ b_dst,
        const float* __restrict__ attn_l, const float* __restrict__ attn_r,
        unsigned short* __restrict__ w_lr, float* __restrict__ c_lr,
        const int* __restrict__ dst, int* __restrict__ deg) {
    __shared__ float tile[32][33];
    int b = blockIdx.x, t = threadIdx.x;
    if (b < 256) {
        int bi = b >> 4, bj = b & 15;
        for (int i = t; i < 1024; i += 256) {
            int r = i >> 5, c = i & 31;
            tile[r][c] = W_val[(size_t)(bi * 32 + r) * HF + bj * 32 + c];
        }
        __syncthreads();
        for (int i = t; i < 1024; i += 256) {
            int r = i >> 5, c = i & 31;
            Wt[(size_t)(bj * 32 + r) * IN_F + bi * 32 + c] = f2bf(tile[c][r]);
        }
    } else if (b < K14_HIST0) {
        int gid = (b - 256) * 256 + t;
        if (gid < 4096) {
            int k = gid >> 3, h = gid & 7;
            float s = 0.f;
            #pragma unroll 8
            for (int f = 0; f < OUT_F; ++f) s += W_src[k * HF + h * OUT_F + f] * attn_l[h * OUT_F + f];
            w_lr[h * IN_F + k] = f2bf(s);
        } else if (gid < 8192) {
            int g = gid - 4096;
            int k = g >> 3, h = g & 7;
            float s = 0.f;
            #pragma unroll 8
            for (int f = 0; f < OUT_F; ++f) s += W_dst[k * HF + h * OUT_F + f] * attn_r[h * OUT_F + f];
            w_lr[(8 + h) * IN_F + k] = f2bf(s);
        } else if (gid < 8192 + 16) {
            int g = gid - 8192;
            int h = g & 7;
            float s = 0.f;
            if (g < 8) {
                for (int f = 0; f < OUT_F; ++f) s += b_src[h * OUT_F + f] * attn_l[h * OUT_F + f];
                c_lr[h] = s;
            } else {
                for (int f = 0; f < OUT_F; ++f) s += b_dst[h * OUT_F + f] * attn_r[h * OUT_F + f];
                c_lr[8 + h] = s;
            }
        }
    } else {
        int e = (b - K14_HIST0) * 256 + t;
        if (e < N_EDGES) atomicAdd(&deg[dst[e]], 1);
    }
}

// ---------------------------------------------------------------------------
// KS: single-dispatch exclusive scan (redundant-prefix per block, no serial).
// ---------------------------------------------------------------------------
__global__ __launch_bounds__(1024) void kS_scan(const int* __restrict__ deg,
                                                int* __restrict__ offs,
                                                int* __restrict__ cursor) {
    __shared__ int wsum[16];
    __shared__ int base_s;
    int b = blockIdx.x, t = threadIdx.x;
    int lane = t & 63, wid = t >> 6;

    int pre = 0;
    for (int i = t; i < b * 1024; i += 1024) pre += deg[i];
    #pragma unroll
    for (int off = 32; off; off >>= 1) pre += __shfl_down(pre, (unsigned)off, 64);
    if (lane == 0) wsum[wid] = pre;
    __syncthreads();
    if (t == 0) {
        int s = 0;
        for (int i = 0; i < 16; ++i) s += wsum[i];
        base_s = s;
    }
    __syncthreads();
    int base = base_s;
    __syncthreads();

    int i = b * 1024 + t;
    int v = (i < N_NODES) ? deg[i] : 0;
    int x = v;
    #pragma unroll
    for (int off = 1; off < 64; off <<= 1) {
        int y = __shfl_up(x, (unsigned)off, 64);
        if (lane >= off) x += y;
    }
    if (lane == 63) wsum[wid] = x;
    __syncthreads();
    if (wid == 0) {
        int s = (lane < 16) ? wsum[lane] : 0;
        #pragma unroll
        for (int off = 1; off < 16; off <<= 1) {
            int y = __shfl_up(s, (unsigned)off, 64);
            if (lane >= off) s += y;
        }
        if (lane < 16) wsum[lane] = s;
    }
    __syncthreads();
    int woff = wid ? wsum[wid - 1] : 0;
    if (i < N_NODES) {
        int excl = base + woff + x - v;
        offs[i] = excl;
        cursor[i] = excl;
    }
}

// ---------------------------------------------------------------------------
// K3F (R5): fused fp32->bf16 conversion + GEMM + el/er. Replaces k0+k3.
// A is read as fp32 from feat directly, converted in-register while writing
// the XOR-swizzled LDS tile (reg-staging is the legal path for swizzled LDS
// writes; global_load_lds can't swizzle its dest). B (Wt) stays on
// global_load_lds with pre-swizzled source. el/er are computed as a 16-col
// extra MFMA strip: b_e = w_lr[c15][k..k+8]; only bn==0 blocks, wn==0 waves.
// C/D mapping identical to the validated k3 (col=lane&15, row=q*4+rg).
// Pad rows (>=50000): A-loads clamped to row 49999; el/er writes land in the
// N_PAD overrun region (never read).
// ---------------------------------------------------------------------------
constexpr int K3_GRID = (N_PAD / 128) * 4;    // 391*4 = 1564

__global__ __launch_bounds__(256) void k3_fused(
        const float* __restrict__ feat,
        const unsigned short* __restrict__ Bbf,     // Wt [512 cols][512 k]
        const unsigned short* __restrict__ w_lr,    // [16][512] bf16
        const float* __restrict__ c_lr,             // [16]
        const float* __restrict__ bias,
        unsigned short* __restrict__ C,             // feat_v [N_PAD][512]
        float* __restrict__ el, float* __restrict__ er) {
    __shared__ unsigned short As[128 * 64];
    __shared__ unsigned short Bs[128 * 64];
    int tid = threadIdx.x;
    int w = tid >> 6, lane = tid & 63;
    int bm = blockIdx.x >> 2, bn = blockIdx.x & 3;
    int rowBase = bm * 128, colBase = bn * 128;
    int wm = w >> 1, wn = w & 1;
    int c15 = lane & 15, q = lane >> 4;
    bool doE = (bn == 0) && (wn == 0);   // rows wm*64..wm*64+63, cols 0..15

    f32x4 acc[4][4] = {};
    f32x4 accE[4] = {};

    for (int k0 = 0; k0 < IN_F; k0 += 64) {
        // B staging: global_load_lds, pre-swizzled source, linear dest
        #pragma unroll
        for (int rnd = 0; rnd < 4; ++rnd) {
            int e = w * 256 + rnd * 64 + lane;
            int r = e >> 3, p = e & 7;
            int lc = p ^ (r & 7);
            const unsigned short* gB = Bbf + (size_t)(colBase + r) * IN_F + k0 + lc * 8;
            unsigned short* lB = &Bs[e * 8];
            __builtin_amdgcn_global_load_lds(
                (const __attribute__((address_space(1))) unsigned int*)gB,
                (__attribute__((address_space(3))) unsigned int*)lB, 16, 0, 0);
        }
        // A staging: fp32 load (clamped row), convert, swizzled ds_write
        #pragma unroll
        for (int rnd = 0; rnd < 4; ++rnd) {
            int e = w * 256 + rnd * 64 + lane;
            int r = e >> 3, p = e & 7;
            int lc = p ^ (r & 7);
            int row = rowBase + r;
            if (row > N_NODES - 1) row = N_NODES - 1;
            const float* gA = feat + (size_t)row * IN_F + k0 + lc * 8;
            float4 fa = *(const float4*)gA;
            float4 fb = *(const float4*)(gA + 4);
            uint4 pk;
            pk.x = packbf2(fa.x, fa.y); pk.y = packbf2(fa.z, fa.w);
            pk.z = packbf2(fb.x, fb.y); pk.w = packbf2(fb.z, fb.w);
            *(uint4*)&As[e * 8] = pk;
        }
        __syncthreads();

        #pragma unroll
        for (int ks = 0; ks < 2; ++ks) {
            bf16x8 a[4], b[4];
            #pragma unroll
            for (int mi = 0; mi < 4; ++mi) {
                int row = wm * 64 + mi * 16 + c15;
                int pc = (ks * 4 + q) ^ (row & 7);
                a[mi] = *(const bf16x8*)&As[row * 64 + pc * 8];
            }
            #pragma unroll
            for (int nj = 0; nj < 4; ++nj) {
                int row = wn * 64 + nj * 16 + c15;
                int pc = (ks * 4 + q) ^ (row & 7);
                b[nj] = *(const bf16x8*)&Bs[row * 64 + pc * 8];
            }
            #pragma unroll
            for (int mi = 0; mi < 4; ++mi)
                #pragma unroll
                for (int nj = 0; nj < 4; ++nj)
                    acc[mi][nj] = __builtin_amdgcn_mfma_f32_16x16x32_bf16(
                        a[mi], b[nj], acc[mi][nj], 0, 0, 0);
            if (doE) {
                bf16x8 be = *(const bf16x8*)(w_lr + (size_t)c15 * IN_F + k0 + ks * 32 + q * 8);
                #pragma unroll
                for (int mi = 0; mi < 4; ++mi)
                    accE[mi] = __builtin_amdgcn_mfma_f32_16x16x32_bf16(
                        a[mi], be, accE[mi], 0, 0, 0);
            }
        }
        __syncthreads();
    }

    #pragma unroll
    for (int nj = 0; nj < 4; ++nj) {
        int col = colBase + wn * 64 + nj * 16 + c15;
        float bv = bias[col];
        #pragma unroll
        for (int mi = 0; mi < 4; ++mi) {
            int row0 = rowBase + wm * 64 + mi * 16 + q * 4;
            #pragma unroll
            for (int rg = 0; rg < 4; ++rg) {
                C[(size_t)(row0 + rg) * HF + col] = f2bf(acc[mi][nj][rg] + bv);
            }
        }
    }

    if (doE) {
        float cadd = c_lr[c15];
        int side = c15 >> 3, hh = c15 & 7;
        #pragma unroll
        for (int mi = 0; mi < 4; ++mi) {
            int row0 = rowBase + wm * 64 + mi * 16 + q * 4;
            #pragma unroll
            for (int rg = 0; rg < 4; ++rg) {
                float v = accE[mi][rg] + cadd;
                if (side) er[(size_t)(row0 + rg) * 8 + hh] = v;
                else      el[(size_t)(row0 + rg) * 8 + hh] = v;
            }
        }
    }
}

// ---------------------------------------------------------------------------
// K6: counting-sort scatter ONLY (4B payload — minimal scattered write).
// ---------------------------------------------------------------------------
__global__ __launch_bounds__(256) void k6_scatter(
        const int* __restrict__ src, const int* __restrict__ dst,
        int* __restrict__ cursor, int* __restrict__ srcs) {
    int e = blockIdx.x * 256 + threadIdx.x;
    if (e < N_EDGES) {
        int pos = atomicAdd(&cursor[dst[e]], 1);
        srcs[pos] = src[e];
    }
}

// ---------------------------------------------------------------------------
// K8: fused edge-softmax + aggregation — EXACT R0 form (77.4 µs measured,
// the best of 4 structural variants). One WAVE per node; lane owns a 16B
// uint4 chunk (8 bf16 feats, one head = lane>>3). 16B/lane gather is the
// instruction-efficiency sweet spot (2B/lane: 8x VMEM instrs, 2.3x time).
// No min-waves hint (forcing 8/EU spilled acc[] -> 375 MB scratch, 2.3x).
// Persistent/chunked grids measured neutral-to-worse; 4.0-4.2 TB/s L2-fill
// is this gather pattern's service floor. Atomic-free.
// ---------------------------------------------------------------------------
__device__ __forceinline__ void accum8(float* acc, uint4 v, float w) {
    unsigned u;
    u = v.x;
    acc[0] = fmaf(w, __uint_as_float(u << 16), acc[0]);
    acc[1] = fmaf(w, __uint_as_float(u & 0xffff0000u), acc[1]);
    u = v.y;
    acc[2] = fmaf(w, __uint_as_float(u << 16), acc[2]);
    acc[3] = fmaf(w, __uint_as_float(u & 0xffff0000u), acc[3]);
    u = v.z;
    acc[4] = fmaf(w, __uint_as_float(u << 16), acc[4]);
    acc[5] = fmaf(w, __uint_as_float(u & 0xffff0000u), acc[5]);
    u = v.w;
    acc[6] = fmaf(w, __uint_as_float(u << 16), acc[6]);
    acc[7] = fmaf(w, __uint_as_float(u & 0xffff0000u), acc[7]);
}

__global__ __launch_bounds__(256) void k8_agg(
        const int* __restrict__ srcs, const int* __restrict__ offs,
        const int* __restrict__ deg,
        const float* __restrict__ el, const float* __restrict__ er,
        const uint4* __restrict__ feat_v,     // bf16 rows: 64 uint4 per row
        float* __restrict__ out) {
    int lane = threadIdx.x & 63;
    int n = blockIdx.x * 4 + (threadIdx.x >> 6);   // grid 12500*4 = 50000 exact
    int start = offs[n], cnt = deg[n];
    int h = lane >> 3;
    float erh = er[(size_t)n * 8 + h];
    float acc[8] = {};
    float dsum = 0.f;

    for (int base = 0; base < cnt; base += 64) {
        int m = cnt - base; if (m > 64) m = 64;
        int s_all = (lane < m) ? srcs[start + base + lane] : 0;
        int i = 0;
        for (; i + 8 <= m; i += 8) {
            int s[8]; uint4 v[8]; float e[8];
            #pragma unroll
            for (int j = 0; j < 8; ++j) s[j] = __shfl(s_all, i + j, 64);
            #pragma unroll
            for (int j = 0; j < 8; ++j) v[j] = feat_v[(size_t)s[j] * 64 + lane];
            #pragma unroll
            for (int j = 0; j < 8; ++j) e[j] = el[(size_t)s[j] * 8 + h];
            #pragma unroll
            for (int j = 0; j < 8; ++j) {
                float x = e[j] + erh;
                x = (x >= 0.f) ? x : NEG * x;
                float w = __expf(x);
                dsum += w;
                accum8(acc, v[j], w);
            }
        }
        for (; i < m; ++i) {
            int s0 = __shfl(s_all, i, 64);
            uint4 v0 = feat_v[(size_t)s0 * 64 + lane];
            float x = el[(size_t)s0 * 8 + h] + erh;
            x = (x >= 0.f) ? x : NEG * x;
            float w = __expf(x);
            dsum += w;
            accum8(acc, v0, w);
        }
    }

    float dn = 1.f / fmaxf(dsum, 1e-16f);
    float* op = out + (size_t)n * HF + lane * 8;
    *(float4*)op       = make_float4(acc[0] * dn, acc[1] * dn, acc[2] * dn, acc[3] * dn);
    *(float4*)(op + 4) = make_float4(acc[4] * dn, acc[5] * dn, acc[6] * dn, acc[7] * dn);
}

// ---------------------------------------------------------------------------
extern "C" void kernel_launch(void* const* d_in, const int* in_sizes, int n_in,
                              void* d_out, int out_size, void* d_ws, size_t ws_size,
                              hipStream_t stream) {
    const float* feat   = (const float*)d_in[0];
    const int*   src    = (const int*)d_in[1];
    const int*   dst    = (const int*)d_in[2];
    const float* W_src  = (const float*)d_in[3];
    const float* b_src  = (const float*)d_in[4];
    const float* W_dst  = (const float*)d_in[5];
    const float* b_dst  = (const float*)d_in[6];
    const float* W_val  = (const float*)d_in[7];
    const float* b_val  = (const float*)d_in[8];
    const float* attn_l = (const float*)d_in[9];
    const float* attn_r = (const float*)d_in[10];
    float* out = (float*)d_out;

    char* ws = (char*)d_ws;
    size_t off = 0;
    auto alloc = [&](size_t bytes) -> void* {
        void* p = ws + off;
        off += (bytes + 255) & ~(size_t)255;
        return p;
    };

    unsigned short* Wt      = (unsigned short*)alloc((size_t)IN_F * HF * 2);
    unsigned short* feat_v  = (unsigned short*)alloc((size_t)N_PAD * HF * 2);
    unsigned short* w_lr    = (unsigned short*)alloc((size_t)16 * IN_F * 2);
    float* c_lr   = (float*)alloc(16 * 4);
    float* el     = (float*)alloc((size_t)N_PAD * 8 * 4);
    float* er     = (float*)alloc((size_t)N_PAD * 8 * 4);
    int*   deg    = (int*)alloc((size_t)N_NODES * 4);
    int*   offs   = (int*)alloc((size_t)N_NODES * 4);
    int*   cursor = (int*)alloc((size_t)N_NODES * 4);
    int*   srcs   = (int*)alloc((size_t)N_EDGES * 4);
    (void)ws_size; (void)in_sizes; (void)n_in; (void)out_size;

    hipMemsetAsync(deg, 0, (size_t)N_NODES * 4, stream);
    k14_misc<<<K14_BLOCKS, 256, 0, stream>>>(W_val, Wt, W_src, b_src, W_dst, b_dst,
                                             attn_l, attn_r, w_lr, c_lr, dst, deg);
    kS_scan<<<(N_NODES + 1023) / 1024, 1024, 0, stream>>>(deg, offs, cursor);
    k3_fused<<<K3_GRID, 256, 0, stream>>>(feat, Wt, w_lr, c_lr, b_val,
                                          feat_v, el, er);
    k6_scatter<<<(N_EDGES + 255) / 256, 256, 0, stream>>>(src, dst, cursor, srcs);
    k8_agg<<<N_NODES / 4, 256, 0, stream>>>(srcs, offs, deg, el, er,
                                            (const uint4*)feat_v, out);
}

// Round 7
// 355.279 us; speedup vs baseline: 1.0782x; 1.0389x over previous
//
#include <hip/hip_runtime.h>
#include <math.h>

constexpr int N_NODES = 50000;
constexpr int N_PAD   = 50048;    // 391 * 128, padded rows for tile overrun
constexpr int N_EDGES = 400000;
constexpr int IN_F = 512;
constexpr int HEADS = 8;
constexpr int OUT_F = 64;
constexpr int HF = 512;           // HEADS * OUT_F
constexpr float NEG = 0.2f;

typedef __bf16 bf16x8 __attribute__((ext_vector_type(8)));
typedef float  f32x4  __attribute__((ext_vector_type(4)));

__device__ __forceinline__ unsigned short f2bf(float f) {
    unsigned u = __float_as_uint(f);
    u += 0x7fffu + ((u >> 16) & 1u);   // round-to-nearest-even (inputs finite)
    return (unsigned short)(u >> 16);
}
__device__ __forceinline__ unsigned packbf2(float lo, float hi) {
    return (unsigned)f2bf(lo) | ((unsigned)f2bf(hi) << 16);
}

// ---------------------------------------------------------------------------
// K14: merged dispatch — [0,256): W_val transpose->bf16; [256,289): fold
// attention vectors into w_lr (bf16, [16 cols][512 k], col<8 = l-side heads,
// col>=8 = r-side) + c_lr[16] (bias dots); [289,...): dst-degree histogram.
// (deg zeroed by memset.)
// ---------------------------------------------------------------------------
constexpr int K14_HIST0 = 289;
constexpr int K14_BLOCKS = K14_HIST0 + (N_EDGES + 255) / 256;   // 289 + 1563

__global__ __launch_bounds__(256) void k14_misc(
        const float* __restrict__ W_val, unsigned short* __restrict__ Wt,
        const float* __restrict__ W_src, const float* __restrict__ b_src,
        const float* __restrict__ W_dst, const float* __restrict__ b_dst,
        const float* __restrict__ attn_l, const float* __restrict__ attn_r,
        unsigned short* __restrict__ w_lr, float* __restrict__ c_lr,
        const int* __restrict__ dst, int* __restrict__ deg) {
    __shared__ float tile[32][33];
    int b = blockIdx.x, t = threadIdx.x;
    if (b < 256) {
        int bi = b >> 4, bj = b & 15;
        for (int i = t; i < 1024; i += 256) {
            int r = i >> 5, c = i & 31;
            tile[r][c] = W_val[(size_t)(bi * 32 + r) * HF + bj * 32 + c];
        }
        __syncthreads();
        for (int i = t; i < 1024; i += 256) {
            int r = i >> 5, c = i & 31;
            Wt[(size_t)(bj * 32 + r) * IN_F + bi * 32 + c] = f2bf(tile[c][r]);
        }
    } else if (b < K14_HIST0) {
        int gid = (b - 256) * 256 + t;
        if (gid < 4096) {
            int k = gid >> 3, h = gid & 7;
            float s = 0.f;
            #pragma unroll 8
            for (int f = 0; f < OUT_F; ++f) s += W_src[k * HF + h * OUT_F + f] * attn_l[h * OUT_F + f];
            w_lr[h * IN_F + k] = f2bf(s);
        } else if (gid < 8192) {
            int g = gid - 4096;
            int k = g >> 3, h = g & 7;
            float s = 0.f;
            #pragma unroll 8
            for (int f = 0; f < OUT_F; ++f) s += W_dst[k * HF + h * OUT_F + f] * attn_r[h * OUT_F + f];
            w_lr[(8 + h) * IN_F + k] = f2bf(s);
        } else if (gid < 8192 + 16) {
            int g = gid - 8192;
            int h = g & 7;
            float s = 0.f;
            if (g < 8) {
                for (int f = 0; f < OUT_F; ++f) s += b_src[h * OUT_F + f] * attn_l[h * OUT_F + f];
                c_lr[h] = s;
            } else {
                for (int f = 0; f < OUT_F; ++f) s += b_dst[h * OUT_F + f] * attn_r[h * OUT_F + f];
                c_lr[8 + h] = s;
            }
        }
    } else {
        int e = (b - K14_HIST0) * 256 + t;
        if (e < N_EDGES) atomicAdd(&deg[dst[e]], 1);
    }
}

// ---------------------------------------------------------------------------
// KS: single-dispatch exclusive scan (redundant-prefix per block, no serial).
// ---------------------------------------------------------------------------
__global__ __launch_bounds__(1024) void kS_scan(const int* __restrict__ deg,
                                                int* __restrict__ offs,
                                                int* __restrict__ cursor) {
    __shared__ int wsum[16];
    __shared__ int base_s;
    int b = blockIdx.x, t = threadIdx.x;
    int lane = t & 63, wid = t >> 6;

    int pre = 0;
    for (int i = t; i < b * 1024; i += 1024) pre += deg[i];
    #pragma unroll
    for (int off = 32; off; off >>= 1) pre += __shfl_down(pre, (unsigned)off, 64);
    if (lane == 0) wsum[wid] = pre;
    __syncthreads();
    if (t == 0) {
        int s = 0;
        for (int i = 0; i < 16; ++i) s += wsum[i];
        base_s = s;
    }
    __syncthreads();
    int base = base_s;
    __syncthreads();

    int i = b * 1024 + t;
    int v = (i < N_NODES) ? deg[i] : 0;
    int x = v;
    #pragma unroll
    for (int off = 1; off < 64; off <<= 1) {
        int y = __shfl_up(x, (unsigned)off, 64);
        if (lane >= off) x += y;
    }
    if (lane == 63) wsum[wid] = x;
    __syncthreads();
    if (wid == 0) {
        int s = (lane < 16) ? wsum[lane] : 0;
        #pragma unroll
        for (int off = 1; off < 16; off <<= 1) {
            int y = __shfl_up(s, (unsigned)off, 64);
            if (lane >= off) s += y;
        }
        if (lane < 16) wsum[lane] = s;
    }
    __syncthreads();
    int woff = wid ? wsum[wid - 1] : 0;
    if (i < N_NODES) {
        int excl = base + woff + x - v;
        offs[i] = excl;
        cursor[i] = excl;
    }
}

// ---------------------------------------------------------------------------
// K36 (R6): mega-dispatch = pipelined fused GEMM + edge scatter.
//  - Blocks [0,1568): fp32->bf16 + GEMM + el/er strip (R5 math, unchanged),
//    with (a) double-buffered As/Bs and T14 async-split: A regs + B
//    global_load_lds for tile k+1 issued BEFORE the MFMA phase on tile k,
//    A convert+ds_write after; ONE barrier per K-step (R5: 2 barriers,
//    synchronous A staging -> latency-bound, MfmaUtil 11%, occ 17%).
//    (b) XCD-pinned mapping: the 4 bn-tiles of each bm land on one XCD,
//    temporally adjacent -> A-panel HBM-fetched once (R5: FETCH 202 MB =
//    ~2x A over-fetch across XCD L2s).
//  - Blocks [1568,...): counting-sort scatter (was k6) — independent work
//    co-resident with the low-occupancy GEMM, removing its serial ~tens of
//    µs from the timeline. Both need only k14+kS done; k8 needs both.
// ---------------------------------------------------------------------------
constexpr int K3_GEMM = 8 * 49 * 4;                         // 1568 (4 dummies)
constexpr int K36_BLOCKS = K3_GEMM + (N_EDGES + 255) / 256; // + 1563

__global__ __launch_bounds__(256) void k36_gemm_scatter(
        const float* __restrict__ feat,
        const unsigned short* __restrict__ Bbf,     // Wt [512 cols][512 k]
        const unsigned short* __restrict__ w_lr,    // [16][512] bf16
        const float* __restrict__ c_lr,             // [16]
        const float* __restrict__ bias,
        unsigned short* __restrict__ C,             // feat_v [N_PAD][512]
        float* __restrict__ el, float* __restrict__ er,
        const int* __restrict__ src, const int* __restrict__ dst,
        int* __restrict__ cursor, int* __restrict__ srcs) {
    __shared__ unsigned short As[2][128 * 64];
    __shared__ unsigned short Bs[2][128 * 64];

    int b = blockIdx.x;
    if (b >= K3_GEMM) {                   // -------- scatter path (was k6)
        int e = (b - K3_GEMM) * 256 + threadIdx.x;
        if (e < N_EDGES) {
            int pos = atomicAdd(&cursor[dst[e]], 1);
            srcs[pos] = src[e];
        }
        return;
    }

    // -------- GEMM path: XCD-pinned tile mapping
    int xcd = b & 7;
    int r0 = b >> 3;                      // 0..195
    int bn = r0 & 3;
    int bm = xcd + 8 * (r0 >> 2);         // bmg 0..48
    if (bm >= N_PAD / 128) return;        // 391 bms; 4 dummy blocks exit

    int tid = threadIdx.x;
    int w = tid >> 6, lane = tid & 63;
    int rowBase = bm * 128, colBase = bn * 128;
    int wm = w >> 1, wn = w & 1;
    int c15 = lane & 15, q = lane >> 4;
    bool doE = (bn == 0) && (wn == 0);    // el/er strip owner

    f32x4 acc[4][4] = {};
    f32x4 accE[4] = {};

    int e0 = w * 256 + lane;              // staging slot base (+ rnd*64)
    float4 pa[4], pb[4];                  // A prefetch regs (fp32, 32 VGPR)

    auto LOADA = [&](int k0) {
        #pragma unroll
        for (int rnd = 0; rnd < 4; ++rnd) {
            int e = e0 + rnd * 64;
            int r = e >> 3, p = e & 7;
            int lc = p ^ (r & 7);         // XOR chunk swizzle (match reads)
            int row = rowBase + r;
            if (row > N_NODES - 1) row = N_NODES - 1;   // pad-row clamp
            const float* g = feat + (size_t)row * IN_F + k0 + lc * 8;
            pa[rnd] = *(const float4*)g;
            pb[rnd] = *(const float4*)(g + 4);
        }
    };
    auto ISSUEB = [&](int k0, int buf) {
        #pragma unroll
        for (int rnd = 0; rnd < 4; ++rnd) {
            int e = e0 + rnd * 64;
            int r = e >> 3, p = e & 7;
            int lc = p ^ (r & 7);
            const unsigned short* g = Bbf + (size_t)(colBase + r) * IN_F + k0 + lc * 8;
            __builtin_amdgcn_global_load_lds(
                (const __attribute__((address_space(1))) unsigned int*)g,
                (__attribute__((address_space(3))) unsigned int*)&Bs[buf][e * 8],
                16, 0, 0);
        }
    };
    auto WRITEA = [&](int buf) {
        #pragma unroll
        for (int rnd = 0; rnd < 4; ++rnd) {
            int e = e0 + rnd * 64;
            uint4 pk;
            pk.x = packbf2(pa[rnd].x, pa[rnd].y);
            pk.y = packbf2(pa[rnd].z, pa[rnd].w);
            pk.z = packbf2(pb[rnd].x, pb[rnd].y);
            pk.w = packbf2(pb[rnd].z, pb[rnd].w);
            *(uint4*)&As[buf][e * 8] = pk;
        }
    };

    // prologue: stage tile 0 into buffer 0
    LOADA(0);
    ISSUEB(0, 0);
    WRITEA(0);
    __syncthreads();

    for (int k0 = 0; k0 < IN_F; k0 += 64) {
        int cur = (k0 >> 6) & 1, nxt = cur ^ 1;
        bool more = (k0 + 64) < IN_F;
        if (more) { LOADA(k0 + 64); ISSUEB(k0 + 64, nxt); }   // prefetch k+1

        #pragma unroll
        for (int ks = 0; ks < 2; ++ks) {
            bf16x8 a[4], bb[4];
            #pragma unroll
            for (int mi = 0; mi < 4; ++mi) {
                int row = wm * 64 + mi * 16 + c15;
                int pc = (ks * 4 + q) ^ (row & 7);
                a[mi] = *(const bf16x8*)&As[cur][row * 64 + pc * 8];
            }
            #pragma unroll
            for (int nj = 0; nj < 4; ++nj) {
                int row = wn * 64 + nj * 16 + c15;
                int pc = (ks * 4 + q) ^ (row & 7);
                bb[nj] = *(const bf16x8*)&Bs[cur][row * 64 + pc * 8];
            }
            #pragma unroll
            for (int mi = 0; mi < 4; ++mi)
                #pragma unroll
                for (int nj = 0; nj < 4; ++nj)
                    acc[mi][nj] = __builtin_amdgcn_mfma_f32_16x16x32_bf16(
                        a[mi], bb[nj], acc[mi][nj], 0, 0, 0);
            if (doE) {
                bf16x8 be = *(const bf16x8*)(w_lr + (size_t)c15 * IN_F + k0 + ks * 32 + q * 8);
                #pragma unroll
                for (int mi = 0; mi < 4; ++mi)
                    accE[mi] = __builtin_amdgcn_mfma_f32_16x16x32_bf16(
                        a[mi], be, accE[mi], 0, 0, 0);
            }
        }

        if (more) WRITEA(nxt);            // A-loads had the MFMA phase to land
        __syncthreads();                  // drains B gload_lds + A ds_writes
    }

    #pragma unroll
    for (int nj = 0; nj < 4; ++nj) {
        int col = colBase + wn * 64 + nj * 16 + c15;
        float bv = bias[col];
        #pragma unroll
        for (int mi = 0; mi < 4; ++mi) {
            int row0 = rowBase + wm * 64 + mi * 16 + q * 4;
            #pragma unroll
            for (int rg = 0; rg < 4; ++rg) {
                C[(size_t)(row0 + rg) * HF + col] = f2bf(acc[mi][nj][rg] + bv);
            }
        }
    }

    if (doE) {
        float cadd = c_lr[c15];
        int side = c15 >> 3, hh = c15 & 7;
        #pragma unroll
        for (int mi = 0; mi < 4; ++mi) {
            int row0 = rowBase + wm * 64 + mi * 16 + q * 4;
            #pragma unroll
            for (int rg = 0; rg < 4; ++rg) {
                float v = accE[mi][rg] + cadd;
                if (side) er[(size_t)(row0 + rg) * 8 + hh] = v;
                else      el[(size_t)(row0 + rg) * 8 + hh] = v;
            }
        }
    }
}

// ---------------------------------------------------------------------------
// K8: fused edge-softmax + aggregation — EXACT R0 form (77.4 µs measured,
// the best of 4 structural variants). One WAVE per node; lane owns a 16B
// uint4 chunk (8 bf16 feats, one head = lane>>3). 16B/lane gather is the
// instruction-efficiency sweet spot (2B/lane: 8x VMEM instrs, 2.3x time).
// No min-waves hint (forcing 8/EU spilled acc[] -> 375 MB scratch, 2.3x).
// Persistent/chunked grids measured neutral-to-worse; 4.0-4.2 TB/s L2-fill
// is this gather pattern's service floor. Atomic-free.
// ---------------------------------------------------------------------------
__device__ __forceinline__ void accum8(float* acc, uint4 v, float w) {
    unsigned u;
    u = v.x;
    acc[0] = fmaf(w, __uint_as_float(u << 16), acc[0]);
    acc[1] = fmaf(w, __uint_as_float(u & 0xffff0000u), acc[1]);
    u = v.y;
    acc[2] = fmaf(w, __uint_as_float(u << 16), acc[2]);
    acc[3] = fmaf(w, __uint_as_float(u & 0xffff0000u), acc[3]);
    u = v.z;
    acc[4] = fmaf(w, __uint_as_float(u << 16), acc[4]);
    acc[5] = fmaf(w, __uint_as_float(u & 0xffff0000u), acc[5]);
    u = v.w;
    acc[6] = fmaf(w, __uint_as_float(u << 16), acc[6]);
    acc[7] = fmaf(w, __uint_as_float(u & 0xffff0000u), acc[7]);
}

__global__ __launch_bounds__(256) void k8_agg(
        const int* __restrict__ srcs, const int* __restrict__ offs,
        const int* __restrict__ deg,
        const float* __restrict__ el, const float* __restrict__ er,
        const uint4* __restrict__ feat_v,     // bf16 rows: 64 uint4 per row
        float* __restrict__ out) {
    int lane = threadIdx.x & 63;
    int n = blockIdx.x * 4 + (threadIdx.x >> 6);   // grid 12500*4 = 50000 exact
    int start = offs[n], cnt = deg[n];
    int h = lane >> 3;
    float erh = er[(size_t)n * 8 + h];
    float acc[8] = {};
    float dsum = 0.f;

    for (int base = 0; base < cnt; base += 64) {
        int m = cnt - base; if (m > 64) m = 64;
        int s_all = (lane < m) ? srcs[start + base + lane] : 0;
        int i = 0;
        for (; i + 8 <= m; i += 8) {
            int s[8]; uint4 v[8]; float e[8];
            #pragma unroll
            for (int j = 0; j < 8; ++j) s[j] = __shfl(s_all, i + j, 64);
            #pragma unroll
            for (int j = 0; j < 8; ++j) v[j] = feat_v[(size_t)s[j] * 64 + lane];
            #pragma unroll
            for (int j = 0; j < 8; ++j) e[j] = el[(size_t)s[j] * 8 + h];
            #pragma unroll
            for (int j = 0; j < 8; ++j) {
                float x = e[j] + erh;
                x = (x >= 0.f) ? x : NEG * x;
                float w = __expf(x);
                dsum += w;
                accum8(acc, v[j], w);
            }
        }
        for (; i < m; ++i) {
            int s0 = __shfl(s_all, i, 64);
            uint4 v0 = feat_v[(size_t)s0 * 64 + lane];
            float x = el[(size_t)s0 * 8 + h] + erh;
            x = (x >= 0.f) ? x : NEG * x;
            float w = __expf(x);
            dsum += w;
            accum8(acc, v0, w);
        }
    }

    float dn = 1.f / fmaxf(dsum, 1e-16f);
    float* op = out + (size_t)n * HF + lane * 8;
    *(float4*)op       = make_float4(acc[0] * dn, acc[1] * dn, acc[2] * dn, acc[3] * dn);
    *(float4*)(op + 4) = make_float4(acc[4] * dn, acc[5] * dn, acc[6] * dn, acc[7] * dn);
}

// ---------------------------------------------------------------------------
extern "C" void kernel_launch(void* const* d_in, const int* in_sizes, int n_in,
                              void* d_out, int out_size, void* d_ws, size_t ws_size,
                              hipStream_t stream) {
    const float* feat   = (const float*)d_in[0];
    const int*   src    = (const int*)d_in[1];
    const int*   dst    = (const int*)d_in[2];
    const float* W_src  = (const float*)d_in[3];
    const float* b_src  = (const float*)d_in[4];
    const float* W_dst  = (const float*)d_in[5];
    const float* b_dst  = (const float*)d_in[6];
    const float* W_val  = (const float*)d_in[7];
    const float* b_val  = (const float*)d_in[8];
    const float* attn_l = (const float*)d_in[9];
    const float* attn_r = (const float*)d_in[10];
    float* out = (float*)d_out;

    char* ws = (char*)d_ws;
    size_t off = 0;
    auto alloc = [&](size_t bytes) -> void* {
        void* p = ws + off;
        off += (bytes + 255) & ~(size_t)255;
        return p;
    };

    unsigned short* Wt      = (unsigned short*)alloc((size_t)IN_F * HF * 2);
    unsigned short* feat_v  = (unsigned short*)alloc((size_t)N_PAD * HF * 2);
    unsigned short* w_lr    = (unsigned short*)alloc((size_t)16 * IN_F * 2);
    float* c_lr   = (float*)alloc(16 * 4);
    float* el     = (float*)alloc((size_t)N_PAD * 8 * 4);
    float* er     = (float*)alloc((size_t)N_PAD * 8 * 4);
    int*   deg    = (int*)alloc((size_t)N_NODES * 4);
    int*   offs   = (int*)alloc((size_t)N_NODES * 4);
    int*   cursor = (int*)alloc((size_t)N_NODES * 4);
    int*   srcs   = (int*)alloc((size_t)N_EDGES * 4);
    (void)ws_size; (void)in_sizes; (void)n_in; (void)out_size;

    hipMemsetAsync(deg, 0, (size_t)N_NODES * 4, stream);
    k14_misc<<<K14_BLOCKS, 256, 0, stream>>>(W_val, Wt, W_src, b_src, W_dst, b_dst,
                                             attn_l, attn_r, w_lr, c_lr, dst, deg);
    kS_scan<<<(N_NODES + 1023) / 1024, 1024, 0, stream>>>(deg, offs, cursor);
    k36_gemm_scatter<<<K36_BLOCKS, 256, 0, stream>>>(feat, Wt, w_lr, c_lr, b_val,
                                                     feat_v, el, er,
                                                     src, dst, cursor, srcs);
    k8_agg<<<N_NODES / 4, 256, 0, stream>>>(srcs, offs, deg, el, er,
                                            (const uint4*)feat_v, out);
}